// Round 13
// baseline (193.763 us; speedup 1.0000x reference)
//
#include <hip/hip_runtime.h>
#include <hip/hip_bf16.h>

// ---------------------------------------------------------------------------
// QLayer: per-type 2-layer MLP.
//   h   = relu(x_t @ W1_t + b1_t)       [16384x512]@[512x1024]   (x4 types)
//   out = h @ W2_t + b2_t, padded to 128 cols                    (x4 types)
// Round 13: break the 8-wave/CU register ceiling. r2-r12 all carried
// acc=128 AGPR + ~108 arch = ~236 unified regs/wave -> 2048/236 = 8 waves/CU
// = ONE barrier-locked block/CU (why every schedule change was null).
// GEMM1 now: 128x128 tile, 256 threads (4 waves 2x2, acc[4][4]=64),
// single 32KB LDS buffer, fused fa-pipeline kept -> ~160 regs/wave ->
// 12 wave slots -> 3 independent blocks/CU (m114 cross-block overlap).
// GEMM2 (HBM floor ~21us) unchanged.
// ---------------------------------------------------------------------------

typedef __attribute__((ext_vector_type(8))) short short8;
typedef __attribute__((ext_vector_type(4))) float f32x4;

#define NT 4
#define NNODE 16384
#define DIN 512
#define DH 1024
#define MAXO 128

static __device__ __forceinline__ ushort f2bf(float f) {
    __hip_bfloat16 h = __float2bfloat16(f);
    return *reinterpret_cast<ushort*>(&h);
}

static __device__ __forceinline__ short8 pack8(const float4 a, const float4 b) {
    union { short8 v; ushort u[8]; } r;
    r.u[0] = f2bf(a.x); r.u[1] = f2bf(a.y); r.u[2] = f2bf(a.z); r.u[3] = f2bf(a.w);
    r.u[4] = f2bf(b.x); r.u[5] = f2bf(b.y); r.u[6] = f2bf(b.z); r.u[7] = f2bf(b.w);
    return r.v;
}

#define GLD(gsrc, ldst)                                                        \
    __builtin_amdgcn_global_load_lds(                                          \
        (const __attribute__((address_space(1))) void*)(gsrc),                 \
        (__attribute__((address_space(3))) void*)(ldst), 16, 0, 0)

// --- W1 transpose+convert: in fp32 [R][Cin] -> out bf16 [Cout][R] ----------
__global__ __launch_bounds__(256) void cvt_w_t_kernel(
    const float* __restrict__ in, ushort* __restrict__ out,
    int R, int Cin, size_t in_tstride, size_t out_tstride) {
    __shared__ float tile[32][33];
    const int t = blockIdx.z;
    in += (size_t)t * in_tstride;
    out += (size_t)t * out_tstride;
    const int c0 = blockIdx.x * 32, r0 = blockIdx.y * 32;
    const int cx = threadIdx.x & 31;
    const int ry = threadIdx.x >> 5;   // 0..7
#pragma unroll
    for (int j = 0; j < 4; ++j) {
        int rr = ry + j * 8;
        int c = c0 + cx;
        tile[rr][cx] = (c < Cin) ? in[(size_t)(r0 + rr) * Cin + c] : 0.0f;
    }
    __syncthreads();
#pragma unroll
    for (int j = 0; j < 4; ++j) {
        int cc = ry + j * 8;
        out[(size_t)(c0 + cc) * R + r0 + cx] = f2bf(tile[cx][cc]);
    }
}

// --- W2 (all 4 types) transpose+convert + b2 pad, one launch ---------------
__global__ __launch_bounds__(256) void cvt_w2_kernel(
    const float* __restrict__ w0, const float* __restrict__ w1,
    const float* __restrict__ w2, const float* __restrict__ w3,
    const float* __restrict__ c0_, const float* __restrict__ c1_,
    const float* __restrict__ c2_, const float* __restrict__ c3_,
    ushort* __restrict__ out, float* __restrict__ b2p) {
    __shared__ float tile[32][33];
    const int t = blockIdx.z;
    const int Cin = (t == 0) ? 128 : (t == 1) ? 96 : (t == 2) ? 64 : 32;
    const float* in = (t == 0) ? w0 : (t == 1) ? w1 : (t == 2) ? w2 : w3;
    ushort* o = out + (size_t)t * MAXO * DH;
    const int c0 = blockIdx.x * 32, r0 = blockIdx.y * 32;
    const int cx = threadIdx.x & 31;
    const int ry = threadIdx.x >> 5;
#pragma unroll
    for (int j = 0; j < 4; ++j) {
        int rr = ry + j * 8;
        int c = c0 + cx;
        tile[rr][cx] = (c < Cin) ? in[(size_t)(r0 + rr) * Cin + c] : 0.0f;
    }
    __syncthreads();
#pragma unroll
    for (int j = 0; j < 4; ++j) {
        int cc = ry + j * 8;
        o[(size_t)(c0 + cc) * DH + r0 + cx] = f2bf(tile[cx][cc]);
    }
    if (blockIdx.x == 0 && blockIdx.y == 0 && threadIdx.x < 128) {
        const float* b = (t == 0) ? c0_ : (t == 1) ? c1_ : (t == 2) ? c2_ : c3_;
        const int n = threadIdx.x;
        b2p[t * 128 + n] = (n < Cin) ? b[n] : 0.0f;
    }
}

// ---------------------------------------------------------------------------
// GEMM1: 128x128 tile, 256 threads = 4 waves (2x2), wave tile 64x64,
// acc[4][4]=64 regs. Single 32KB LDS buffer (A 16KB + B 16KB) -> with
// ~160 unified regs/wave: 12 wave slots -> 3 blocks/CU co-resident.
// Fused fp32->bf16 A path: fa regs (8x float4) hold tile i's X during
// tile i-1; per tile: {B GLDs; ds_write fa; refill fa (tile i+1);
// vmcnt(8) [fa refills stay in flight] lgkmcnt(0); barrier; compute;
// barrier}. XOR swizzle byte(r,c16) = r*128 + ((c16*16)^((r&7)<<4)).
// Grid 4096 = 4t x 128m x 8n (n fastest), chunked XCD swizzle (A L2 reuse).
// MFMA operands swapped (D-row dim = n) -> vectorized bf16 stores.
// ---------------------------------------------------------------------------
__global__ __launch_bounds__(256) void gemm1q(
    const float* __restrict__ x0, const float* __restrict__ x1,
    const float* __restrict__ x2, const float* __restrict__ x3,
    const ushort* __restrict__ W1T, const float* __restrict__ b1,
    ushort* __restrict__ H) {
    constexpr int K = DIN;                 // 512
    __shared__ char lds[32768];            // A 16KB @0, B 16KB @16384

    // chunked XCD-bijective swizzle (grid 4096 % 8 == 0)
    const int cpx = gridDim.x >> 3;
    const int g = blockIdx.x;
    const int wg = (g & 7) * cpx + (g >> 3);
    const int t = wg >> 10;                // 1024 tiles per type
    const int rmn = wg & 1023;
    const int m0 = (rmn >> 3) * 128;       // 128 m-tiles
    const int n0 = (rmn & 7) * 128;        // 8 n-tiles (fastest -> L2 reuse)

    const float* Af = (t == 0) ? x0 : (t == 1) ? x1 : (t == 2) ? x2 : x3;
    const ushort* Bp = W1T + (size_t)t * DH * K;
    const float* bias = b1 + (size_t)t * DH;
    ushort* Ht = H + (size_t)t * NNODE * DH;

    const int tid = threadIdx.x;
    const int lane = tid & 63;
    const int w = tid >> 6;
    const int wm = w >> 1, wn = w & 1;     // 2x2 waves, 64x64 each
    const int lrow = lane & 15, lgrp = lane >> 4;

    // staging: 4 chunks/thread each (tile = 1024 x 16B chunks / 256 thr)
    const float* af32src[4];
    const ushort* bsrc[4];
    int adst[4], bdst[4];
#pragma unroll
    for (int j = 0; j < 4; ++j) {
        const int c = j * 256 + tid;       // chunk 0..1023
        const int r = c >> 3;              // row 0..127
        const int c8 = c & 7;
        const int cb = (c8 * 16) ^ ((r & 7) << 4);
        af32src[j] = Af + (size_t)(m0 + r) * K + c8 * 8;
        adst[j] = r * 128 + cb;            // swizzled dst for ds_write_b128
        bsrc[j] = Bp + (size_t)(n0 + r) * K + (cb >> 1);  // pre-swizzled src
        bdst[j] = 16384 + c * 16;          // linear dst for global_load_lds
    }

    f32x4 acc[4][4] = {};
    float4 fa[4][2];                       // fp32 A regs (32 VGPRs)

    // prologue: fa <- tile 0
#pragma unroll
    for (int j = 0; j < 4; ++j) {
        fa[j][0] = *reinterpret_cast<const float4*>(af32src[j]);
        fa[j][1] = *reinterpret_cast<const float4*>(af32src[j] + 4);
    }

    for (int i = 0; i < K / 64; ++i) {
        const int kt = i * 64;
        const bool more = (i + 1 < K / 64);

        // ---- stage tile i (buffer free: barrier 2 of prev iter passed) ----
#pragma unroll
        for (int j = 0; j < 4; ++j) GLD(bsrc[j] + kt, lds + bdst[j]);
        // publish fa (tile i data; landed: loaded >= 1 compute phase ago)
#pragma unroll
        for (int j = 0; j < 4; ++j)
            *reinterpret_cast<short8*>(lds + adst[j]) = pack8(fa[j][0], fa[j][1]);
        asm volatile("" ::: "memory");     // keep refill after ds_writes
        if (more) {
#pragma unroll
            for (int j = 0; j < 4; ++j) {
                fa[j][0] = *reinterpret_cast<const float4*>(af32src[j] + kt + 64);
                fa[j][1] = *reinterpret_cast<const float4*>(af32src[j] + kt + 68);
            }
            // retire the 4 B GLDs; the 8 fa refills (newest) stay in flight
            asm volatile("s_waitcnt vmcnt(8) lgkmcnt(0)" ::: "memory");
        } else {
            asm volatile("s_waitcnt vmcnt(0) lgkmcnt(0)" ::: "memory");
        }
        __builtin_amdgcn_s_barrier();      // publish tile i
        asm volatile("" ::: "memory");

        // ---- compute tile i ----
#pragma unroll
        for (int kkk = 0; kkk < 2; ++kkk) {
            short8 bfr[4], af[4];
#pragma unroll
            for (int ni = 0; ni < 4; ++ni) {
                const int br = wn * 64 + ni * 16 + lrow;
                const int kb = (kkk * 64 + lgrp * 16) ^ ((br & 7) << 4);
                bfr[ni] = *(const short8*)(lds + 16384 + br * 128 + kb);
            }
#pragma unroll
            for (int ml = 0; ml < 4; ++ml) {
                const int ar = wm * 64 + ml * 16 + lrow;
                const int kb = (kkk * 64 + lgrp * 16) ^ ((ar & 7) << 4);
                af[ml] = *(const short8*)(lds + ar * 128 + kb);
            }
#pragma unroll
            for (int ml = 0; ml < 4; ++ml)
#pragma unroll
                for (int ni = 0; ni < 4; ++ni)
                    acc[ml][ni] = __builtin_amdgcn_mfma_f32_16x16x32_bf16(
                        bfr[ni], af[ml], acc[ml][ni], 0, 0, 0);
        }

        if (more) {
            asm volatile("" ::: "memory");
            __builtin_amdgcn_s_barrier();  // free buffer for restage
            asm volatile("" ::: "memory");
        }
    }

    // --- epilogue: lane holds 4 consecutive n; m = ...+lrow ----------------
#pragma unroll
    for (int ni = 0; ni < 4; ++ni) {
        const int ncol = n0 + wn * 64 + ni * 16 + lgrp * 4;
        const float4 bv = *reinterpret_cast<const float4*>(&bias[ncol]);
#pragma unroll
        for (int ml = 0; ml < 4; ++ml) {
            const int row = m0 + wm * 64 + ml * 16 + lrow;
            float v0 = fmaxf(acc[ml][ni][0] + bv.x, 0.0f);
            float v1 = fmaxf(acc[ml][ni][1] + bv.y, 0.0f);
            float v2 = fmaxf(acc[ml][ni][2] + bv.z, 0.0f);
            float v3 = fmaxf(acc[ml][ni][3] + bv.w, 0.0f);
            uint2 p;
            p.x = (uint)f2bf(v0) | ((uint)f2bf(v1) << 16);
            p.y = (uint)f2bf(v2) | ((uint)f2bf(v3) << 16);
            *reinterpret_cast<uint2*>(&Ht[(size_t)row * DH + ncol]) = p;
        }
    }
}

// ---------------------------------------------------------------------------
// GEMM2 (r12 structure, at HBM floor): out = H @ W2T^T + b2. BM=256, BN=128,
// BK=64, single 48KB buffer, 1-barrier-pair per K-tile, GLD staging.
// ---------------------------------------------------------------------------
__global__ __launch_bounds__(512, 1) void gemm2s(
    const ushort* __restrict__ Hbase, const ushort* __restrict__ Bbase,
    const float* __restrict__ biasbase, float* __restrict__ Cbase,
    int N, int K, int MT) {
    constexpr int NF = 2;
    constexpr int ABYTES = 256 * 64 * 2;   // 32 KB
    __shared__ char lds[ABYTES + 128 * 64 * 2];

    const int cpx = gridDim.x >> 3;
    const int g = blockIdx.x;
    const int wg = (g & 7) * cpx + (g >> 3);
    const int t = wg / MT;
    const int m0 = (wg % MT) * 256;

    const ushort* A = Hbase + (size_t)t * NNODE * DH;
    const ushort* Bp = Bbase + (size_t)t * MAXO * DH;
    const float* bias = biasbase + (size_t)t * MAXO;

    const int tid = threadIdx.x;
    const int lane = tid & 63;
    const int w = tid >> 6;
    const int wm = w >> 2, wn = w & 3;
    const int lrow = lane & 15, lgrp = lane >> 4;

    const ushort* abfsrc[4];
    int adst[4];
#pragma unroll
    for (int j = 0; j < 4; ++j) {
        const int c = j * 512 + tid;
        const int r = c >> 3;
        const int cb = ((c & 7) * 16) ^ ((r & 7) << 4);
        abfsrc[j] = A + (size_t)(m0 + r) * K + (cb >> 1);
        adst[j] = c * 16;
    }
    const ushort* bsrc[2];
    int bdst[2];
#pragma unroll
    for (int j = 0; j < 2; ++j) {
        const int c = j * 512 + tid;
        const int r = c >> 3;
        const int cb = ((c & 7) * 16) ^ ((r & 7) << 4);
        bsrc[j] = Bp + (size_t)r * K + (cb >> 1);
        bdst[j] = ABYTES + c * 16;
    }

    f32x4 acc[8][NF] = {};
    const int NK = K / 64;

    for (int i = 0; i < NK; ++i) {
        const int kt = i * 64;
#pragma unroll
        for (int j = 0; j < 4; ++j) GLD(abfsrc[j] + kt, lds + adst[j]);
#pragma unroll
        for (int j = 0; j < 2; ++j) GLD(bsrc[j] + kt, lds + bdst[j]);
        asm volatile("s_waitcnt vmcnt(0)" ::: "memory");
        __builtin_amdgcn_s_barrier();
        asm volatile("" ::: "memory");

#pragma unroll
        for (int kkk = 0; kkk < 2; ++kkk) {
            short8 bfr[NF], af[8];
#pragma unroll
            for (int ni = 0; ni < NF; ++ni) {
                const int br = wn * (NF * 16) + ni * 16 + lrow;
                const int kb = (kkk * 64 + lgrp * 16) ^ ((br & 7) << 4);
                bfr[ni] = *(const short8*)(lds + ABYTES + br * 128 + kb);
            }
#pragma unroll
            for (int ml = 0; ml < 8; ++ml) {
                const int ar = wm * 128 + ml * 16 + lrow;
                const int kb = (kkk * 64 + lgrp * 16) ^ ((ar & 7) << 4);
                af[ml] = *(const short8*)(lds + ar * 128 + kb);
            }
#pragma unroll
            for (int ml = 0; ml < 8; ++ml)
#pragma unroll
                for (int ni = 0; ni < NF; ++ni)
                    acc[ml][ni] = __builtin_amdgcn_mfma_f32_16x16x32_bf16(
                        bfr[ni], af[ml], acc[ml][ni], 0, 0, 0);
        }

        if (i + 1 < NK) {
            asm volatile("" ::: "memory");
            __builtin_amdgcn_s_barrier();
            asm volatile("" ::: "memory");
        }
    }

    const int wnoff = wn * (NF * 16);
    const int wmoff = m0 + wm * 128;
#pragma unroll
    for (int ni = 0; ni < NF; ++ni) {
        const int ncol = wnoff + ni * 16 + lgrp * 4;
        const float4 bv = *reinterpret_cast<const float4*>(&bias[ncol]);
#pragma unroll
        for (int mi = 0; mi < 8; ++mi) {
            const int row = wmoff + mi * 16 + lrow;
            float4 p;
            p.x = acc[mi][ni][0] + bv.x;
            p.y = acc[mi][ni][1] + bv.y;
            p.z = acc[mi][ni][2] + bv.z;
            p.w = acc[mi][ni][3] + bv.w;
            *reinterpret_cast<float4*>(
                &Cbase[(size_t)t * NNODE * MAXO + (size_t)row * N + ncol]) = p;
        }
    }
}

extern "C" void kernel_launch(void* const* d_in, const int* in_sizes, int n_in,
                              void* d_out, int out_size, void* d_ws, size_t ws_size,
                              hipStream_t stream) {
    const float* x0 = (const float*)d_in[0];
    const float* x1 = (const float*)d_in[1];
    const float* x2 = (const float*)d_in[2];
    const float* x3 = (const float*)d_in[3];
    // d_in[4] = node_type (unused: nodes are blocked by type already)
    const float* W1 = (const float*)d_in[5];
    const float* b1 = (const float*)d_in[6];
    const float* W2[4] = {(const float*)d_in[7], (const float*)d_in[9],
                          (const float*)d_in[11], (const float*)d_in[13]};
    const float* b2[4] = {(const float*)d_in[8], (const float*)d_in[10],
                          (const float*)d_in[12], (const float*)d_in[14]};

    // workspace layout (bytes):
    //   H    bf16 [4][16384][1024]  134217728
    //   W1T  bf16 [4][1024][512]      4194304
    //   W2T  bf16 [4][128][1024]      1048576
    //   b2p  f32  [4][128]                2048
    char* ws = (char*)d_ws;
    ushort* H   = (ushort*)ws;
    ushort* W1T = (ushort*)(ws + 134217728ull);
    ushort* W2T = (ushort*)(ws + 134217728ull + 4194304ull);
    float*  b2p = (float*)(ws + 134217728ull + 4194304ull + 1048576ull);

    // weight conversions (small)
    cvt_w_t_kernel<<<dim3(32, 16, 4), 256, 0, stream>>>(
        W1, W1T, DIN, DH, (size_t)DIN * DH, (size_t)DH * DIN);
    cvt_w2_kernel<<<dim3(4, 32, 4), 256, 0, stream>>>(
        W2[0], W2[1], W2[2], W2[3], b2[0], b2[1], b2[2], b2[3], W2T, b2p);

    // layer 1: H = relu(X @ W1 + b1), fused fp32->bf16, 3 blocks/CU target
    // grid: 4 types x 128 m-tiles x 8 n-tiles = 4096 (n fastest)
    gemm1q<<<4096, 256, 0, stream>>>(x0, x1, x2, x3, W1T, b1, H);

    // layer 2: out = H @ W2 + b2 (padded cols exactly 0), fp32 out
    // grid: 4 types x 64 m-tiles = 256
    gemm2s<<<256, 512, 0, stream>>>(H, W2T, b2p, (float*)d_out,
                                    MAXO, DH, NNODE / 256);
}

// Round 14
// 170.366 us; speedup vs baseline: 1.1373x; 1.1373x over previous
//
#include <hip/hip_runtime.h>
#include <hip/hip_bf16.h>

// ---------------------------------------------------------------------------
// QLayer: per-type 2-layer MLP.
//   h   = relu(x_t @ W1_t + b1_t)       [16384x512]@[512x1024]   (x4 types)
//   out = h @ W2_t + b2_t, padded to 128 cols                    (x4 types)
// Round 14: r13 + __launch_bounds__(256,3). r13's 108 arch + 64 acc = 172
// unified regs/wave missed the 3-waves/SIMD threshold (512/3=170) by 2
// registers -> stayed at 2 waves/SIMD like every round this session. The
// (256,3) bound forces arch<=106 -> 3 blocks/CU (12 waves) = the m97/m114
// cross-block-overlap regime, tested for the first time. GEMM2 restored to
// the r9/r11 double-buffered version (HBM floor ~21us).
// ---------------------------------------------------------------------------

typedef __attribute__((ext_vector_type(8))) short short8;
typedef __attribute__((ext_vector_type(4))) float f32x4;

#define NT 4
#define NNODE 16384
#define DIN 512
#define DH 1024
#define MAXO 128

static __device__ __forceinline__ ushort f2bf(float f) {
    __hip_bfloat16 h = __float2bfloat16(f);
    return *reinterpret_cast<ushort*>(&h);
}

static __device__ __forceinline__ short8 pack8(const float4 a, const float4 b) {
    union { short8 v; ushort u[8]; } r;
    r.u[0] = f2bf(a.x); r.u[1] = f2bf(a.y); r.u[2] = f2bf(a.z); r.u[3] = f2bf(a.w);
    r.u[4] = f2bf(b.x); r.u[5] = f2bf(b.y); r.u[6] = f2bf(b.z); r.u[7] = f2bf(b.w);
    return r.v;
}

#define GLD(gsrc, ldst)                                                        \
    __builtin_amdgcn_global_load_lds(                                          \
        (const __attribute__((address_space(1))) void*)(gsrc),                 \
        (__attribute__((address_space(3))) void*)(ldst), 16, 0, 0)

// --- W1 transpose+convert: in fp32 [R][Cin] -> out bf16 [Cout][R] ----------
__global__ __launch_bounds__(256) void cvt_w_t_kernel(
    const float* __restrict__ in, ushort* __restrict__ out,
    int R, int Cin, size_t in_tstride, size_t out_tstride) {
    __shared__ float tile[32][33];
    const int t = blockIdx.z;
    in += (size_t)t * in_tstride;
    out += (size_t)t * out_tstride;
    const int c0 = blockIdx.x * 32, r0 = blockIdx.y * 32;
    const int cx = threadIdx.x & 31;
    const int ry = threadIdx.x >> 5;   // 0..7
#pragma unroll
    for (int j = 0; j < 4; ++j) {
        int rr = ry + j * 8;
        int c = c0 + cx;
        tile[rr][cx] = (c < Cin) ? in[(size_t)(r0 + rr) * Cin + c] : 0.0f;
    }
    __syncthreads();
#pragma unroll
    for (int j = 0; j < 4; ++j) {
        int cc = ry + j * 8;
        out[(size_t)(c0 + cc) * R + r0 + cx] = f2bf(tile[cx][cc]);
    }
}

// --- W2 (all 4 types) transpose+convert + b2 pad, one launch ---------------
__global__ __launch_bounds__(256) void cvt_w2_kernel(
    const float* __restrict__ w0, const float* __restrict__ w1,
    const float* __restrict__ w2, const float* __restrict__ w3,
    const float* __restrict__ c0_, const float* __restrict__ c1_,
    const float* __restrict__ c2_, const float* __restrict__ c3_,
    ushort* __restrict__ out, float* __restrict__ b2p) {
    __shared__ float tile[32][33];
    const int t = blockIdx.z;
    const int Cin = (t == 0) ? 128 : (t == 1) ? 96 : (t == 2) ? 64 : 32;
    const float* in = (t == 0) ? w0 : (t == 1) ? w1 : (t == 2) ? w2 : w3;
    ushort* o = out + (size_t)t * MAXO * DH;
    const int c0 = blockIdx.x * 32, r0 = blockIdx.y * 32;
    const int cx = threadIdx.x & 31;
    const int ry = threadIdx.x >> 5;
#pragma unroll
    for (int j = 0; j < 4; ++j) {
        int rr = ry + j * 8;
        int c = c0 + cx;
        tile[rr][cx] = (c < Cin) ? in[(size_t)(r0 + rr) * Cin + c] : 0.0f;
    }
    __syncthreads();
#pragma unroll
    for (int j = 0; j < 4; ++j) {
        int cc = ry + j * 8;
        o[(size_t)(c0 + cc) * DH + r0 + cx] = f2bf(tile[cx][cc]);
    }
    if (blockIdx.x == 0 && blockIdx.y == 0 && threadIdx.x < 128) {
        const float* b = (t == 0) ? c0_ : (t == 1) ? c1_ : (t == 2) ? c2_ : c3_;
        const int n = threadIdx.x;
        b2p[t * 128 + n] = (n < Cin) ? b[n] : 0.0f;
    }
}

// ---------------------------------------------------------------------------
// GEMM1: 128x128 tile, 256 threads = 4 waves (2x2), wave tile 64x64,
// acc[4][4]=64 AGPR. Single 32KB LDS buffer. __launch_bounds__(256,3)
// forces arch VGPR <= ~106 -> 3 waves/SIMD -> 3 blocks/CU co-resident:
// one block's stage phase hides under two blocks' compute (m114).
// Fused fp32->bf16 A path: fa regs hold tile i's X during tile i-1;
// per tile: {B GLDs; ds_write fa; refill fa (tile i+1); vmcnt(8)
// [fa refills stay in flight] lgkmcnt(0); barrier; compute; barrier}.
// XOR swizzle byte(r,c16) = r*128 + ((c16*16)^((r&7)<<4)).
// Grid 4096 = 4t x 128m x 8n (n fastest), chunked XCD swizzle.
// MFMA operands swapped (D-row dim = n) -> vectorized bf16 stores.
// ---------------------------------------------------------------------------
__global__ __launch_bounds__(256, 3) void gemm1q(
    const float* __restrict__ x0, const float* __restrict__ x1,
    const float* __restrict__ x2, const float* __restrict__ x3,
    const ushort* __restrict__ W1T, const float* __restrict__ b1,
    ushort* __restrict__ H) {
    constexpr int K = DIN;                 // 512
    __shared__ char lds[32768];            // A 16KB @0, B 16KB @16384

    // chunked XCD-bijective swizzle (grid 4096 % 8 == 0)
    const int cpx = gridDim.x >> 3;
    const int g = blockIdx.x;
    const int wg = (g & 7) * cpx + (g >> 3);
    const int t = wg >> 10;                // 1024 tiles per type
    const int rmn = wg & 1023;
    const int m0 = (rmn >> 3) * 128;       // 128 m-tiles
    const int n0 = (rmn & 7) * 128;        // 8 n-tiles (fastest -> L2 reuse)

    const float* Af = (t == 0) ? x0 : (t == 1) ? x1 : (t == 2) ? x2 : x3;
    const ushort* Bp = W1T + (size_t)t * DH * K;
    const float* bias = b1 + (size_t)t * DH;
    ushort* Ht = H + (size_t)t * NNODE * DH;

    const int tid = threadIdx.x;
    const int lane = tid & 63;
    const int w = tid >> 6;
    const int wm = w >> 1, wn = w & 1;     // 2x2 waves, 64x64 each
    const int lrow = lane & 15, lgrp = lane >> 4;

    // staging: 4 chunks/thread each (tile = 1024 x 16B chunks / 256 thr)
    const float* af32src[4];
    const ushort* bsrc[4];
    int adst[4], bdst[4];
#pragma unroll
    for (int j = 0; j < 4; ++j) {
        const int c = j * 256 + tid;       // chunk 0..1023
        const int r = c >> 3;              // row 0..127
        const int c8 = c & 7;
        const int cb = (c8 * 16) ^ ((r & 7) << 4);
        af32src[j] = Af + (size_t)(m0 + r) * K + c8 * 8;
        adst[j] = r * 128 + cb;            // swizzled dst for ds_write_b128
        bsrc[j] = Bp + (size_t)(n0 + r) * K + (cb >> 1);  // pre-swizzled src
        bdst[j] = 16384 + c * 16;          // linear dst for global_load_lds
    }

    f32x4 acc[4][4] = {};
    float4 fa[4][2];                       // fp32 A regs (32 VGPRs)

    // prologue: fa <- tile 0
#pragma unroll
    for (int j = 0; j < 4; ++j) {
        fa[j][0] = *reinterpret_cast<const float4*>(af32src[j]);
        fa[j][1] = *reinterpret_cast<const float4*>(af32src[j] + 4);
    }

    for (int i = 0; i < K / 64; ++i) {
        const int kt = i * 64;
        const bool more = (i + 1 < K / 64);

        // ---- stage tile i (buffer free: barrier 2 of prev iter passed) ----
#pragma unroll
        for (int j = 0; j < 4; ++j) GLD(bsrc[j] + kt, lds + bdst[j]);
        // publish fa (tile i data; landed: loaded >= 1 compute phase ago)
#pragma unroll
        for (int j = 0; j < 4; ++j)
            *reinterpret_cast<short8*>(lds + adst[j]) = pack8(fa[j][0], fa[j][1]);
        asm volatile("" ::: "memory");     // keep refill after ds_writes
        if (more) {
#pragma unroll
            for (int j = 0; j < 4; ++j) {
                fa[j][0] = *reinterpret_cast<const float4*>(af32src[j] + kt + 64);
                fa[j][1] = *reinterpret_cast<const float4*>(af32src[j] + kt + 68);
            }
            // retire the 4 B GLDs; the 8 fa refills (newest) stay in flight
            asm volatile("s_waitcnt vmcnt(8) lgkmcnt(0)" ::: "memory");
        } else {
            asm volatile("s_waitcnt vmcnt(0) lgkmcnt(0)" ::: "memory");
        }
        __builtin_amdgcn_s_barrier();      // publish tile i
        asm volatile("" ::: "memory");

        // ---- compute tile i ----
#pragma unroll
        for (int kkk = 0; kkk < 2; ++kkk) {
            short8 bfr[4], af[4];
#pragma unroll
            for (int ni = 0; ni < 4; ++ni) {
                const int br = wn * 64 + ni * 16 + lrow;
                const int kb = (kkk * 64 + lgrp * 16) ^ ((br & 7) << 4);
                bfr[ni] = *(const short8*)(lds + 16384 + br * 128 + kb);
            }
#pragma unroll
            for (int ml = 0; ml < 4; ++ml) {
                const int ar = wm * 64 + ml * 16 + lrow;
                const int kb = (kkk * 64 + lgrp * 16) ^ ((ar & 7) << 4);
                af[ml] = *(const short8*)(lds + ar * 128 + kb);
            }
#pragma unroll
            for (int ml = 0; ml < 4; ++ml)
#pragma unroll
                for (int ni = 0; ni < 4; ++ni)
                    acc[ml][ni] = __builtin_amdgcn_mfma_f32_16x16x32_bf16(
                        bfr[ni], af[ml], acc[ml][ni], 0, 0, 0);
        }

        if (more) {
            asm volatile("" ::: "memory");
            __builtin_amdgcn_s_barrier();  // free buffer for restage
            asm volatile("" ::: "memory");
        }
    }

    // --- epilogue: lane holds 4 consecutive n; m = ...+lrow ----------------
#pragma unroll
    for (int ni = 0; ni < 4; ++ni) {
        const int ncol = n0 + wn * 64 + ni * 16 + lgrp * 4;
        const float4 bv = *reinterpret_cast<const float4*>(&bias[ncol]);
#pragma unroll
        for (int ml = 0; ml < 4; ++ml) {
            const int row = m0 + wm * 64 + ml * 16 + lrow;
            float v0 = fmaxf(acc[ml][ni][0] + bv.x, 0.0f);
            float v1 = fmaxf(acc[ml][ni][1] + bv.y, 0.0f);
            float v2 = fmaxf(acc[ml][ni][2] + bv.z, 0.0f);
            float v3 = fmaxf(acc[ml][ni][3] + bv.w, 0.0f);
            uint2 p;
            p.x = (uint)f2bf(v0) | ((uint)f2bf(v1) << 16);
            p.y = (uint)f2bf(v2) | ((uint)f2bf(v3) << 16);
            *reinterpret_cast<uint2*>(&Ht[(size_t)row * DH + ncol]) = p;
        }
    }
}

// ---------------------------------------------------------------------------
// GEMM2 (r9/r11 dbuf structure, at HBM floor): out = H @ W2T^T + b2.
// BM=256, BN=128, BK=64 dbuf, 1 barrier/K-tile, GLD staging, XOR swizzle.
// ---------------------------------------------------------------------------
__global__ __launch_bounds__(512, 1) void gemm2k(
    const ushort* __restrict__ Hbase, const ushort* __restrict__ Bbase,
    const float* __restrict__ biasbase, float* __restrict__ Cbase,
    int N, int K, int MT) {
    constexpr int NF = 2;                  // BN=128
    constexpr int NBC = 2;
    constexpr int ABYTES = 256 * 64 * 2;   // 32 KB
    constexpr int BBYTES = 128 * 64 * 2;   // 16 KB
    constexpr int BUF = ABYTES + BBYTES;
    __shared__ char lds[2 * BUF];

    const int cpx = gridDim.x >> 3;
    const int g = blockIdx.x;
    const int wg = (g & 7) * cpx + (g >> 3);
    const int t = wg / MT;
    const int m0 = (wg % MT) * 256;

    const ushort* A = Hbase + (size_t)t * NNODE * DH;
    const ushort* Bp = Bbase + (size_t)t * MAXO * DH;
    const float* bias = biasbase + (size_t)t * MAXO;

    const int tid = threadIdx.x;
    const int lane = tid & 63;
    const int w = tid >> 6;
    const int wm = w >> 2, wn = w & 3;
    const int lrow = lane & 15, lgrp = lane >> 4;

    const ushort* abfsrc[4];
    int adst[4];
#pragma unroll
    for (int j = 0; j < 4; ++j) {
        const int c = j * 512 + tid;
        const int r = c >> 3;
        const int cb = ((c & 7) * 16) ^ ((r & 7) << 4);
        abfsrc[j] = A + (size_t)(m0 + r) * K + (cb >> 1);
        adst[j] = c * 16;
    }
    const ushort* bsrc[NBC];
    int bdst[NBC];
#pragma unroll
    for (int j = 0; j < NBC; ++j) {
        const int c = j * 512 + tid;
        const int r = c >> 3;
        const int cb = ((c & 7) * 16) ^ ((r & 7) << 4);
        bsrc[j] = Bp + (size_t)r * K + (cb >> 1);
        bdst[j] = ABYTES + c * 16;
    }

    f32x4 acc[8][NF] = {};
    const int NK = K / 64;

#pragma unroll
    for (int j = 0; j < 4; ++j) GLD(abfsrc[j], lds + adst[j]);
#pragma unroll
    for (int j = 0; j < NBC; ++j) GLD(bsrc[j], lds + bdst[j]);
    asm volatile("s_waitcnt vmcnt(0)" ::: "memory");
    __builtin_amdgcn_s_barrier();
    asm volatile("" ::: "memory");

    for (int i = 0; i < NK; ++i) {
        const char* cu_ = lds + (i & 1) * BUF;
        char* nx_ = lds + ((i + 1) & 1) * BUF;
        const int ktn = (i + 1) * 64;
        const bool st = (i + 1 < NK);

        if (st) {
#pragma unroll
            for (int j = 0; j < 4; ++j) GLD(abfsrc[j] + ktn, nx_ + adst[j]);
#pragma unroll
            for (int j = 0; j < NBC; ++j) GLD(bsrc[j] + ktn, nx_ + bdst[j]);
        }

#pragma unroll
        for (int kkk = 0; kkk < 2; ++kkk) {
            short8 bfr[NF], af[8];
#pragma unroll
            for (int ni = 0; ni < NF; ++ni) {
                const int br = wn * (NF * 16) + ni * 16 + lrow;
                const int kb = (kkk * 64 + lgrp * 16) ^ ((br & 7) << 4);
                bfr[ni] = *(const short8*)(cu_ + ABYTES + br * 128 + kb);
            }
#pragma unroll
            for (int ml = 0; ml < 8; ++ml) {
                const int ar = wm * 128 + ml * 16 + lrow;
                const int kb = (kkk * 64 + lgrp * 16) ^ ((ar & 7) << 4);
                af[ml] = *(const short8*)(cu_ + ar * 128 + kb);
            }
#pragma unroll
            for (int ml = 0; ml < 8; ++ml)
#pragma unroll
                for (int ni = 0; ni < NF; ++ni)
                    acc[ml][ni] = __builtin_amdgcn_mfma_f32_16x16x32_bf16(
                        bfr[ni], af[ml], acc[ml][ni], 0, 0, 0);
        }

        if (st) {
            asm volatile("s_waitcnt vmcnt(0)" ::: "memory");
            __builtin_amdgcn_s_barrier();
            asm volatile("" ::: "memory");
        }
    }

    const int wnoff = wn * (NF * 16);
    const int wmoff = m0 + wm * 128;
#pragma unroll
    for (int ni = 0; ni < NF; ++ni) {
        const int ncol = wnoff + ni * 16 + lgrp * 4;
        const float4 bv = *reinterpret_cast<const float4*>(&bias[ncol]);
#pragma unroll
        for (int mi = 0; mi < 8; ++mi) {
            const int row = wmoff + mi * 16 + lrow;
            float4 p;
            p.x = acc[mi][ni][0] + bv.x;
            p.y = acc[mi][ni][1] + bv.y;
            p.z = acc[mi][ni][2] + bv.z;
            p.w = acc[mi][ni][3] + bv.w;
            *reinterpret_cast<float4*>(
                &Cbase[(size_t)t * NNODE * MAXO + (size_t)row * N + ncol]) = p;
        }
    }
}

extern "C" void kernel_launch(void* const* d_in, const int* in_sizes, int n_in,
                              void* d_out, int out_size, void* d_ws, size_t ws_size,
                              hipStream_t stream) {
    const float* x0 = (const float*)d_in[0];
    const float* x1 = (const float*)d_in[1];
    const float* x2 = (const float*)d_in[2];
    const float* x3 = (const float*)d_in[3];
    // d_in[4] = node_type (unused: nodes are blocked by type already)
    const float* W1 = (const float*)d_in[5];
    const float* b1 = (const float*)d_in[6];
    const float* W2[4] = {(const float*)d_in[7], (const float*)d_in[9],
                          (const float*)d_in[11], (const float*)d_in[13]};
    const float* b2[4] = {(const float*)d_in[8], (const float*)d_in[10],
                          (const float*)d_in[12], (const float*)d_in[14]};

    // workspace layout (bytes):
    //   H    bf16 [4][16384][1024]  134217728
    //   W1T  bf16 [4][1024][512]      4194304
    //   W2T  bf16 [4][128][1024]      1048576
    //   b2p  f32  [4][128]                2048
    char* ws = (char*)d_ws;
    ushort* H   = (ushort*)ws;
    ushort* W1T = (ushort*)(ws + 134217728ull);
    ushort* W2T = (ushort*)(ws + 134217728ull + 4194304ull);
    float*  b2p = (float*)(ws + 134217728ull + 4194304ull + 1048576ull);

    // weight conversions (small)
    cvt_w_t_kernel<<<dim3(32, 16, 4), 256, 0, stream>>>(
        W1, W1T, DIN, DH, (size_t)DIN * DH, (size_t)DH * DIN);
    cvt_w2_kernel<<<dim3(4, 32, 4), 256, 0, stream>>>(
        W2[0], W2[1], W2[2], W2[3], b2[0], b2[1], b2[2], b2[3], W2T, b2p);

    // layer 1: H = relu(X @ W1 + b1), fused fp32->bf16, 3 blocks/CU target
    // grid: 4 types x 128 m-tiles x 8 n-tiles = 4096 (n fastest)
    gemm1q<<<4096, 256, 0, stream>>>(x0, x1, x2, x3, W1T, b1, H);

    // layer 2: out = H @ W2 + b2 (padded cols exactly 0), fp32 out
    // grid: 4 types x 64 m-tiles = 256
    gemm2k<<<256, 512, 0, stream>>>(H, W2T, b2p, (float*)d_out,
                                    MAXO, DH, NNODE / 256);
}